// Round 6
// baseline (573.156 us; speedup 1.0000x reference)
//
#include <hip/hip_runtime.h>

#define VV 512
#define FF 64
#define OO 64
#define YELEMS 8388608  // shorts per y tensor (256*64*512)

using f32x4 = __attribute__((ext_vector_type(4))) float;
using s16x8 = __attribute__((ext_vector_type(8))) short;
using u16x4 = __attribute__((ext_vector_type(4))) unsigned short;

__device__ __forceinline__ short f2bf(float f) {
    union { float f; unsigned int u; } v; v.f = f;
    unsigned int u = v.u;
    u += 0x7fffu + ((u >> 16) & 1u);
    return (short)(u >> 16);
}
__device__ __forceinline__ float bf2f(unsigned short u) {
    union { unsigned int u; float f; } v; v.u = ((unsigned int)u) << 16; return v.f;
}
__device__ __forceinline__ int swz(int row) { return (row >> 1) & 7; }

// ---------------- Kernel 1: y_k[bt] = x[bt] @ Theta_k, stored TRANSPOSED ----------------
// yT[k][(bt*64 + o)*512 + u]  (bf16)
__global__ __launch_bounds__(256, 4)
void y_kernel(const float* __restrict__ x, const float* __restrict__ Theta,
              unsigned short* __restrict__ yT)
{
    __shared__ __align__(16) unsigned char smem[32768];
    short* xT = (short*)(smem);

    const int tid = threadIdx.x, lane = tid & 63, q = tid >> 6;
    const int g = lane >> 4, nbase = lane & 15;
    const int bt = blockIdx.x >> 3;
    const int u0 = (blockIdx.x & 7) * 64;

    {
        const float* xp = x + ((size_t)(bt * VV + u0 + lane)) * FF + q * 16;
        float4 a0 = ((const float4*)xp)[0];
        float4 a1 = ((const float4*)xp)[1];
        float4 a2 = ((const float4*)xp)[2];
        float4 a3 = ((const float4*)xp)[3];
        float v[16] = {a0.x,a0.y,a0.z,a0.w, a1.x,a1.y,a1.z,a1.w,
                       a2.x,a2.y,a2.z,a2.w, a3.x,a3.y,a3.z,a3.w};
        s16x8 p0, p1;
        #pragma unroll
        for (int e = 0; e < 8; ++e) { p0[e] = f2bf(v[e]); p1[e] = f2bf(v[8 + e]); }
        const int fs = swz(lane);
        *(s16x8*)&xT[lane * 64 + (((q * 2)     ^ fs) * 8)] = p0;
        *(s16x8*)&xT[lane * 64 + (((q * 2 + 1) ^ fs) * 8)] = p1;
    }
    #pragma unroll
    for (int k = 0; k < 3; ++k) {
        short* tk = (short*)(smem + 8192 + k * 8192);
        s16x8 p0, p1;
        #pragma unroll
        for (int e = 0; e < 8; ++e) {
            p0[e] = f2bf(Theta[k * FF * OO + (q * 16 + e) * OO + lane]);
            p1[e] = f2bf(Theta[k * FF * OO + (q * 16 + 8 + e) * OO + lane]);
        }
        const int fs = swz(lane);
        *(s16x8*)&tk[lane * 64 + (((q * 2)     ^ fs) * 8)] = p0;
        *(s16x8*)&tk[lane * 64 + (((q * 2 + 1) ^ fs) * 8)] = p1;
    }
    __syncthreads();

    f32x4 zero = {0.f, 0.f, 0.f, 0.f};
    f32x4 acc[3][4];
    #pragma unroll
    for (int k = 0; k < 3; ++k)
        #pragma unroll
        for (int nt = 0; nt < 4; ++nt) acc[k][nt] = zero;

    const int mrow = q * 16 + nbase;
    const int moff = mrow * 64, ms = swz(mrow);
    #pragma unroll
    for (int kk = 0; kk < 2; ++kk) {
        const int slotA = kk * 4 + g;
        s16x8 a = *(const s16x8*)&xT[moff + ((slotA ^ ms) * 8)];
        #pragma unroll
        for (int nt = 0; nt < 4; ++nt) {
            const int nrow = nt * 16 + nbase;
            const int nad = nrow * 64 + ((slotA ^ swz(nrow)) * 8);
            #pragma unroll
            for (int k = 0; k < 3; ++k) {
                s16x8 b = *(const s16x8*)&((short*)(smem + 8192 + k * 8192))[nad];
                acc[k][nt] = __builtin_amdgcn_mfma_f32_16x16x32_bf16(a, b, acc[k][nt], 0, 0, 0);
            }
        }
    }
    #pragma unroll
    for (int k = 0; k < 3; ++k) {
        #pragma unroll
        for (int nt = 0; nt < 4; ++nt) {
            const int o = nt * 16 + nbase;
            const int u = u0 + q * 16 + g * 4;
            u16x4 pk;
            #pragma unroll
            for (int r = 0; r < 4; ++r) pk[r] = (unsigned short)f2bf(acc[k][nt][r]);
            *(u16x4*)&yT[(size_t)k * YELEMS + ((size_t)(bt * 64 + o)) * VV + u] = pk;
        }
    }
}

// ---------------- Kernel 2: barrier-free Chebyshev conv, max-occupancy ----------------
// No LDS, no barriers, VGPR<=64 -> 8 blocks/CU (32 waves/CU). TLP hides latency.
__global__ __launch_bounds__(256, 8)
void cheb_main(const float* __restrict__ S, const float* __restrict__ Att,
               const unsigned short* __restrict__ yT, float* __restrict__ out)
{
    const int tid = threadIdx.x, lane = tid & 63, q = tid >> 6;
    const int g = lane >> 4, nbase = lane & 15;

    // XCD-friendly decode: the 8 v-tiles of one bt share wg%8 -> same XCD
    const int wg = blockIdx.x;
    const int bt = (wg & 7) + ((wg >> 6) << 3);
    const int vt = (wg >> 3) & 7;
    const int v0 = vt * 64;
    const int b  = bt >> 4;

    const float* Sbt = S + (size_t)bt * VV * VV;
    const float* Abt = Att + (size_t)b * VV * VV;
    const unsigned short* y0g = yT + (size_t)bt * 64 * VV;
    const unsigned short* y1g = y0g + (size_t)YELEMS;
    const unsigned short* y2g = y0g + (size_t)2 * YELEMS;

    const int mrow = q * 16 + nbase;   // my A-row (local v)
    const int vg   = v0 + mrow;        // global v
    const float* Srow = Sbt + (size_t)vg * VV;
    const float* Scol = Sbt + vg;
    const float* Acol = Abt + vg;

    f32x4 zero = {0.f, 0.f, 0.f, 0.f};
    f32x4 acc[4];
    #pragma unroll
    for (int i = 0; i < 4; ++i) acc[i] = zero;
    float da0 = 0.f, da1 = 0.f, adg = 0.f, sdg = 0.f;

    #pragma unroll
    for (int ut = 0; ut < 8; ++ut) {
        const int u0t = ut * 64;
        #pragma unroll
        for (int kk = 0; kk < 2; ++kk) {
            const int ub = u0t + (kk * 4 + g) * 8;
            // y1 B-fragments (L1/L2-shared across waves)
            s16x8 b10 = *(const s16x8*)&y1g[(size_t)(0 * 16 + nbase) * VV + ub];
            s16x8 b11 = *(const s16x8*)&y1g[(size_t)(1 * 16 + nbase) * VV + ub];
            s16x8 b12 = *(const s16x8*)&y1g[(size_t)(2 * 16 + nbase) * VV + ub];
            s16x8 b13 = *(const s16x8*)&y1g[(size_t)(3 * 16 + nbase) * VV + ub];
            // S row chunk (32B contiguous per lane)
            f32x4 r0 = *(const f32x4*)(Srow + ub);
            f32x4 r1 = *(const f32x4*)(Srow + ub + 4);
            // S/A column scalars + coefficients
            s16x8 a1, a2;
            #pragma unroll
            for (int e = 0; e < 8; ++e) {
                float sc = Scol[(size_t)(ub + e) * VV];
                float av = Acol[(size_t)(ub + e) * VV];
                float rv = (e < 4) ? r0[e] : r1[e - 4];
                float sm = fminf(sc, rv);
                if (e & 1) da1 += sm; else da0 += sm;
                float c1 = -av * sm;
                float c2 = (av + av) * (sm * sm);
                if (ub + e == vg) { c1 = 0.f; c2 = 0.f; adg = av; sdg = sm; }
                a1[e] = f2bf(c1);
                a2[e] = f2bf(c2);
            }
            acc[0] = __builtin_amdgcn_mfma_f32_16x16x32_bf16(a1, b10, acc[0], 0, 0, 0);
            acc[1] = __builtin_amdgcn_mfma_f32_16x16x32_bf16(a1, b11, acc[1], 0, 0, 0);
            acc[2] = __builtin_amdgcn_mfma_f32_16x16x32_bf16(a1, b12, acc[2], 0, 0, 0);
            acc[3] = __builtin_amdgcn_mfma_f32_16x16x32_bf16(a1, b13, acc[3], 0, 0, 0);
            // y2 B-fragments (reuse registers of b1*)
            s16x8 b20 = *(const s16x8*)&y2g[(size_t)(0 * 16 + nbase) * VV + ub];
            s16x8 b21 = *(const s16x8*)&y2g[(size_t)(1 * 16 + nbase) * VV + ub];
            s16x8 b22 = *(const s16x8*)&y2g[(size_t)(2 * 16 + nbase) * VV + ub];
            s16x8 b23 = *(const s16x8*)&y2g[(size_t)(3 * 16 + nbase) * VV + ub];
            acc[0] = __builtin_amdgcn_mfma_f32_16x16x32_bf16(a2, b20, acc[0], 0, 0, 0);
            acc[1] = __builtin_amdgcn_mfma_f32_16x16x32_bf16(a2, b21, acc[1], 0, 0, 0);
            acc[2] = __builtin_amdgcn_mfma_f32_16x16x32_bf16(a2, b22, acc[2], 0, 0, 0);
            acc[3] = __builtin_amdgcn_mfma_f32_16x16x32_bf16(a2, b23, acc[3], 0, 0, 0);
        }
    }

    // reduce deg / diag over the 4 g-group lanes (bits 4,5 of lane id)
    float da = da0 + da1;
    da  += __shfl_xor(da, 16);  da  += __shfl_xor(da, 32);
    adg += __shfl_xor(adg, 16); adg += __shfl_xor(adg, 32);
    sdg += __shfl_xor(sdg, 16); sdg += __shfl_xor(sdg, 32);

    float* obt = out + (size_t)bt * VV * OO;
    #pragma unroll
    for (int r = 0; r < 4; ++r) {
        const int vloc = q * 16 + g * 4 + r;
        const int src  = g * 4 + r;
        const float Ad = __shfl(adg, src);
        const float dv = __shfl(da,  src);
        const float Sd = __shfl(sdg, src);
        const float Ld = dv - Sd - 1.0f;
        const float w1 = Ad * Ld;
        const float w2 = Ad * (2.0f * Ld * Ld - 1.0f);
        const int vgr = v0 + vloc;
        #pragma unroll
        for (int nt = 0; nt < 4; ++nt) {
            const int oo = nt * 16 + nbase;
            const size_t yi = (size_t)oo * VV + vgr;
            float y0v = bf2f(y0g[yi]);
            float y1v = bf2f(y1g[yi]);
            float y2v = bf2f(y2g[yi]);
            float val = acc[nt][r] + Ad * y0v + w1 * y1v + w2 * y2v;
            obt[(size_t)vgr * OO + oo] = fmaxf(val, 0.0f);
        }
    }
}

extern "C" void kernel_launch(void* const* d_in, const int* in_sizes, int n_in,
                              void* d_out, int out_size, void* d_ws, size_t ws_size,
                              hipStream_t stream) {
    (void)in_sizes; (void)n_in; (void)ws_size; (void)out_size;
    const float* x   = (const float*)d_in[0];
    const float* Att = (const float*)d_in[1];
    const float* S   = (const float*)d_in[2];
    const float* Th  = (const float*)d_in[3];
    float* outp = (float*)d_out;
    unsigned short* yT = (unsigned short*)d_ws;  // needs 50,331,648 B
    hipLaunchKernelGGL(y_kernel, dim3(2048), dim3(256), 0, stream, x, Th, yT);
    hipLaunchKernelGGL(cheb_main, dim3(2048), dim3(256), 0, stream, S, Att, yT, outp);
}

// Round 7
// 302.467 us; speedup vs baseline: 1.8949x; 1.8949x over previous
//
#include <hip/hip_runtime.h>

#define VV 512
#define FF 64
#define OO 64
#define YELEMS 8388608  // shorts per bf16 y tensor (256*64*512)

// ---- workspace layout (bytes) ----
#define C1_OFF    0u
#define C2_OFF    67108864u
#define Y1F8_OFF  134217728u
#define Y2F8_OFF  142606336u
#define YB_OFF    150994944u
#define DEGP_OFF  201326592u
#define SDG_OFF   205520896u
#define ADG_OFF   206045184u
#define WS_NEED   206569472u

using f32x4 = __attribute__((ext_vector_type(4))) float;
using s16x8 = __attribute__((ext_vector_type(8))) short;
using u16x4 = __attribute__((ext_vector_type(4))) unsigned short;

__device__ __forceinline__ short f2bf(float f) {
    union { float f; unsigned int u; } v; v.f = f;
    unsigned int u = v.u;
    u += 0x7fffu + ((u >> 16) & 1u);
    return (short)(u >> 16);
}
__device__ __forceinline__ float bf2f(unsigned short u) {
    union { unsigned int u; float f; } v; v.u = ((unsigned int)u) << 16; return v.f;
}
__device__ __forceinline__ int swz(int row) { return (row >> 1) & 7; }

// =====================================================================
// Kernel A: coefficient tiles -> fp8, transposed [bt][v][u]; deg partials
// =====================================================================
__device__ __forceinline__ void coef_pass(
    const float (*Tuv)[65], const float (*Tvu)[65], const float (*Auv)[65],
    float (*degred)[64], unsigned char* c1out, unsigned char* c2out,
    int tid, bool isdiag, float* SdgW, float* AdgW)
{
    const int uq = (tid & 15) * 4;
    const int vrow = tid >> 4;
    float dd0 = 0.f, dd1 = 0.f, dd2 = 0.f, dd3 = 0.f;
    #pragma unroll
    for (int it = 0; it < 4; ++it) {
        const int v = vrow + it * 16;
        float c1v[4], c2v[4];
        #pragma unroll
        for (int e = 0; e < 4; ++e) {
            float sm = fminf(Tuv[uq + e][v], Tvu[v][uq + e]);
            float a  = Auv[uq + e][v];
            if (e == 0) dd0 += sm; else if (e == 1) dd1 += sm;
            else if (e == 2) dd2 += sm; else dd3 += sm;
            float c1 = -a * sm;
            float c2 = (a + a) * (sm * sm);
            if (isdiag && (uq + e == v)) {
                c1 = 0.f; c2 = 0.f;
                SdgW[v] = sm; AdgW[v] = a;
            }
            c1v[e] = c1; c2v[e] = c2;
        }
        int w1 = __builtin_amdgcn_cvt_pk_fp8_f32(c1v[0], c1v[1], 0, false);
        w1     = __builtin_amdgcn_cvt_pk_fp8_f32(c1v[2], c1v[3], w1, true);
        int w2 = __builtin_amdgcn_cvt_pk_fp8_f32(c2v[0], c2v[1], 0, false);
        w2     = __builtin_amdgcn_cvt_pk_fp8_f32(c2v[2], c2v[3], w2, true);
        *(int*)(c1out + (size_t)v * VV + uq) = w1;
        *(int*)(c2out + (size_t)v * VV + uq) = w2;
    }
    degred[vrow][uq + 0] = dd0;
    degred[vrow][uq + 1] = dd1;
    degred[vrow][uq + 2] = dd2;
    degred[vrow][uq + 3] = dd3;
}

__global__ __launch_bounds__(256, 2)
void coef_kernel(const float* __restrict__ S, const float* __restrict__ Att,
                 unsigned char* __restrict__ ws)
{
    __shared__ float Tij[64][65];
    __shared__ float Tji[64][65];
    __shared__ float Aij[64][65];
    __shared__ float Aji[64][65];
    __shared__ float degA[16][64];
    __shared__ float degB[16][64];

    const int tid = threadIdx.x;
    const int bt = blockIdx.x / 36;
    int p = blockIdx.x - bt * 36;
    int i = 0;
    while (p >= 8 - i) { p -= 8 - i; ++i; }
    const int j = i + p;
    const int b = bt >> 4;
    const int u0i = i * 64, u0j = j * 64;

    const float* Sbt = S + (size_t)bt * VV * VV;
    const float* Abt = Att + (size_t)b * VV * VV;

    // stage 4 tiles (coalesced float4 reads, conflict-free b32 LDS writes)
    {
        const int r = tid >> 2, c4 = (tid & 3) * 16;
        const float* gij = Sbt + (size_t)(u0i + r) * VV + u0j + c4;
        const float* gji = Sbt + (size_t)(u0j + r) * VV + u0i + c4;
        const float* aij = Abt + (size_t)(u0i + r) * VV + u0j + c4;
        const float* aji = Abt + (size_t)(u0j + r) * VV + u0i + c4;
        #pragma unroll
        for (int w = 0; w < 4; ++w) {
            float4 t = ((const float4*)gij)[w];
            Tij[r][c4 + w * 4 + 0] = t.x; Tij[r][c4 + w * 4 + 1] = t.y;
            Tij[r][c4 + w * 4 + 2] = t.z; Tij[r][c4 + w * 4 + 3] = t.w;
        }
        #pragma unroll
        for (int w = 0; w < 4; ++w) {
            float4 t = ((const float4*)gji)[w];
            Tji[r][c4 + w * 4 + 0] = t.x; Tji[r][c4 + w * 4 + 1] = t.y;
            Tji[r][c4 + w * 4 + 2] = t.z; Tji[r][c4 + w * 4 + 3] = t.w;
        }
        #pragma unroll
        for (int w = 0; w < 4; ++w) {
            float4 t = ((const float4*)aij)[w];
            Aij[r][c4 + w * 4 + 0] = t.x; Aij[r][c4 + w * 4 + 1] = t.y;
            Aij[r][c4 + w * 4 + 2] = t.z; Aij[r][c4 + w * 4 + 3] = t.w;
        }
        #pragma unroll
        for (int w = 0; w < 4; ++w) {
            float4 t = ((const float4*)aji)[w];
            Aji[r][c4 + w * 4 + 0] = t.x; Aji[r][c4 + w * 4 + 1] = t.y;
            Aji[r][c4 + w * 4 + 2] = t.z; Aji[r][c4 + w * 4 + 3] = t.w;
        }
    }
    __syncthreads();

    unsigned char* c1w = ws + C1_OFF + (size_t)bt * (VV * VV);
    unsigned char* c2w = ws + C2_OFF + (size_t)bt * (VV * VV);
    float* SdgW = (float*)(ws + SDG_OFF) + (size_t)bt * VV;
    float* AdgW = (float*)(ws + ADG_OFF) + (size_t)bt * VV;
    float* degpW = (float*)(ws + DEGP_OFF) + (size_t)bt * 8 * VV;

    // pass1: outputs c[v in j][u in i]
    coef_pass(Tij, Tji, Aij, degA,
              c1w + (size_t)u0j * VV + u0i, c2w + (size_t)u0j * VV + u0i,
              tid, (i == j), SdgW + u0j, AdgW + u0j);
    // pass2: outputs c[v in i][u in j]
    if (i < j) {
        coef_pass(Tji, Tij, Aji, degB,
                  c1w + (size_t)u0i * VV + u0j, c2w + (size_t)u0i * VV + u0j,
                  tid, false, SdgW, AdgW);
    }
    __syncthreads();

    if (tid < 64) {
        float s = 0.f;
        #pragma unroll
        for (int k = 0; k < 16; ++k) s += degA[k][tid];
        degpW[(size_t)j * VV + u0i + tid] = s;
    } else if (tid < 128 && i < j) {
        float s = 0.f;
        #pragma unroll
        for (int k = 0; k < 16; ++k) s += degB[k][tid - 64];
        degpW[(size_t)i * VV + u0j + (tid - 64)] = s;
    }
}

// =====================================================================
// Kernel A': y_k = x @ Theta_k ; bf16 [k][bt][o][u] + fp8 copies (k=1,2)
// =====================================================================
__global__ __launch_bounds__(256, 4)
void y_kernel2(const float* __restrict__ x, const float* __restrict__ Theta,
               unsigned char* __restrict__ ws)
{
    __shared__ __align__(16) unsigned char smem[32768];
    short* xT = (short*)(smem);

    const int tid = threadIdx.x, lane = tid & 63, q = tid >> 6;
    const int g = lane >> 4, nbase = lane & 15;
    const int bt = blockIdx.x >> 3;
    const int u0 = (blockIdx.x & 7) * 64;

    {
        const float* xp = x + ((size_t)(bt * VV + u0 + lane)) * FF + q * 16;
        float4 a0 = ((const float4*)xp)[0];
        float4 a1 = ((const float4*)xp)[1];
        float4 a2 = ((const float4*)xp)[2];
        float4 a3 = ((const float4*)xp)[3];
        float v[16] = {a0.x,a0.y,a0.z,a0.w, a1.x,a1.y,a1.z,a1.w,
                       a2.x,a2.y,a2.z,a2.w, a3.x,a3.y,a3.z,a3.w};
        s16x8 p0, p1;
        #pragma unroll
        for (int e = 0; e < 8; ++e) { p0[e] = f2bf(v[e]); p1[e] = f2bf(v[8 + e]); }
        const int fs = swz(lane);
        *(s16x8*)&xT[lane * 64 + (((q * 2)     ^ fs) * 8)] = p0;
        *(s16x8*)&xT[lane * 64 + (((q * 2 + 1) ^ fs) * 8)] = p1;
    }
    #pragma unroll
    for (int k = 0; k < 3; ++k) {
        short* tk = (short*)(smem + 8192 + k * 8192);
        s16x8 p0, p1;
        #pragma unroll
        for (int e = 0; e < 8; ++e) {
            p0[e] = f2bf(Theta[k * FF * OO + (q * 16 + e) * OO + lane]);
            p1[e] = f2bf(Theta[k * FF * OO + (q * 16 + 8 + e) * OO + lane]);
        }
        const int fs = swz(lane);
        *(s16x8*)&tk[lane * 64 + (((q * 2)     ^ fs) * 8)] = p0;
        *(s16x8*)&tk[lane * 64 + (((q * 2 + 1) ^ fs) * 8)] = p1;
    }
    __syncthreads();

    f32x4 zero = {0.f, 0.f, 0.f, 0.f};
    f32x4 acc[3][4];
    #pragma unroll
    for (int k = 0; k < 3; ++k)
        #pragma unroll
        for (int nt = 0; nt < 4; ++nt) acc[k][nt] = zero;

    const int mrow = q * 16 + nbase;
    const int moff = mrow * 64, ms = swz(mrow);
    #pragma unroll
    for (int kk = 0; kk < 2; ++kk) {
        const int slotA = kk * 4 + g;
        s16x8 a = *(const s16x8*)&xT[moff + ((slotA ^ ms) * 8)];
        #pragma unroll
        for (int nt = 0; nt < 4; ++nt) {
            const int nrow = nt * 16 + nbase;
            const int nad = nrow * 64 + ((slotA ^ swz(nrow)) * 8);
            #pragma unroll
            for (int k = 0; k < 3; ++k) {
                s16x8 bb = *(const s16x8*)&((short*)(smem + 8192 + k * 8192))[nad];
                acc[k][nt] = __builtin_amdgcn_mfma_f32_16x16x32_bf16(a, bb, acc[k][nt], 0, 0, 0);
            }
        }
    }
    unsigned short* yb = (unsigned short*)(ws + YB_OFF);
    unsigned char* y1f8 = ws + Y1F8_OFF + (size_t)bt * 32768;
    unsigned char* y2f8 = ws + Y2F8_OFF + (size_t)bt * 32768;
    #pragma unroll
    for (int k = 0; k < 3; ++k) {
        #pragma unroll
        for (int nt = 0; nt < 4; ++nt) {
            const int o = nt * 16 + nbase;
            const int u = u0 + q * 16 + g * 4;
            u16x4 pk;
            #pragma unroll
            for (int r = 0; r < 4; ++r) pk[r] = (unsigned short)f2bf(acc[k][nt][r]);
            *(u16x4*)&yb[(size_t)k * YELEMS + ((size_t)(bt * 64 + o)) * VV + u] = pk;
            if (k == 1) {
                int w = __builtin_amdgcn_cvt_pk_fp8_f32(acc[1][nt][0], acc[1][nt][1], 0, false);
                w     = __builtin_amdgcn_cvt_pk_fp8_f32(acc[1][nt][2], acc[1][nt][3], w, true);
                *(int*)(y1f8 + (size_t)o * VV + u) = w;
            } else if (k == 2) {
                int w = __builtin_amdgcn_cvt_pk_fp8_f32(acc[2][nt][0], acc[2][nt][1], 0, false);
                w     = __builtin_amdgcn_cvt_pk_fp8_f32(acc[2][nt][2], acc[2][nt][3], w, true);
                *(int*)(y2f8 + (size_t)o * VV + u) = w;
            }
        }
    }
}

// =====================================================================
// Kernel B: pure fp8 GEMM (no LDS, no barriers, no VALU in K-loop)
// =====================================================================
__global__ __launch_bounds__(256, 3)
void cheb_b(const unsigned char* __restrict__ ws, float* __restrict__ out)
{
    const int tid = threadIdx.x, lane = tid & 63, q = tid >> 6;
    const int g = lane >> 4, nbase = lane & 15;

    const int wg = blockIdx.x;
    const int bt = (wg & 7) + ((wg >> 6) << 3);
    const int vt = (wg >> 3) & 7;
    const int v0 = vt * 64;

    const int mrow = q * 16 + nbase;
    const int vg   = v0 + mrow;

    const unsigned char* c1r = ws + C1_OFF + (size_t)bt * (VV * VV) + (size_t)vg * VV;
    const unsigned char* c2r = ws + C2_OFF + (size_t)bt * (VV * VV) + (size_t)vg * VV;
    const unsigned char* y1f = ws + Y1F8_OFF + (size_t)bt * 32768 + (size_t)nbase * VV;
    const unsigned char* y2f = ws + Y2F8_OFF + (size_t)bt * 32768 + (size_t)nbase * VV;

    f32x4 zero = {0.f, 0.f, 0.f, 0.f};
    f32x4 acc[4];
    #pragma unroll
    for (int i = 0; i < 4; ++i) acc[i] = zero;

    #pragma unroll
    for (int ut = 0; ut < 8; ++ut) {
        #pragma unroll
        for (int kk = 0; kk < 2; ++kk) {
            const int ub = ut * 64 + (kk * 4 + g) * 8;
            long a1 = *(const long*)(c1r + ub);
            long a2 = *(const long*)(c2r + ub);
            long b10 = *(const long*)(y1f + 0 * 8192 + ub);
            long b11 = *(const long*)(y1f + 1 * 8192 + ub);
            long b12 = *(const long*)(y1f + 2 * 8192 + ub);
            long b13 = *(const long*)(y1f + 3 * 8192 + ub);
            acc[0] = __builtin_amdgcn_mfma_f32_16x16x32_fp8_fp8(a1, b10, acc[0], 0, 0, 0);
            acc[1] = __builtin_amdgcn_mfma_f32_16x16x32_fp8_fp8(a1, b11, acc[1], 0, 0, 0);
            acc[2] = __builtin_amdgcn_mfma_f32_16x16x32_fp8_fp8(a1, b12, acc[2], 0, 0, 0);
            acc[3] = __builtin_amdgcn_mfma_f32_16x16x32_fp8_fp8(a1, b13, acc[3], 0, 0, 0);
            long b20 = *(const long*)(y2f + 0 * 8192 + ub);
            long b21 = *(const long*)(y2f + 1 * 8192 + ub);
            long b22 = *(const long*)(y2f + 2 * 8192 + ub);
            long b23 = *(const long*)(y2f + 3 * 8192 + ub);
            acc[0] = __builtin_amdgcn_mfma_f32_16x16x32_fp8_fp8(a2, b20, acc[0], 0, 0, 0);
            acc[1] = __builtin_amdgcn_mfma_f32_16x16x32_fp8_fp8(a2, b21, acc[1], 0, 0, 0);
            acc[2] = __builtin_amdgcn_mfma_f32_16x16x32_fp8_fp8(a2, b22, acc[2], 0, 0, 0);
            acc[3] = __builtin_amdgcn_mfma_f32_16x16x32_fp8_fp8(a2, b23, acc[3], 0, 0, 0);
        }
    }

    // epilogue: exact diagonal path + combine
    const unsigned short* y0g = (const unsigned short*)(ws + YB_OFF) + (size_t)bt * 64 * VV;
    const unsigned short* y1g = y0g + (size_t)YELEMS;
    const unsigned short* y2g = y0g + (size_t)2 * YELEMS;
    const float* degp = (const float*)(ws + DEGP_OFF) + (size_t)bt * 8 * VV;
    const float* SdgW = (const float*)(ws + SDG_OFF) + (size_t)bt * VV;
    const float* AdgW = (const float*)(ws + ADG_OFF) + (size_t)bt * VV;

    float* obt = out + (size_t)bt * VV * OO;
    #pragma unroll
    for (int r = 0; r < 4; ++r) {
        const int vloc = q * 16 + g * 4 + r;
        const int vgr = v0 + vloc;
        float dv = 0.f;
        #pragma unroll
        for (int s = 0; s < 8; ++s) dv += degp[(size_t)s * VV + vgr];
        const float Ad = AdgW[vgr];
        const float Sd = SdgW[vgr];
        const float Ld = dv - Sd - 1.0f;
        const float w1 = Ad * Ld;
        const float w2 = Ad * (2.0f * Ld * Ld - 1.0f);
        #pragma unroll
        for (int nt = 0; nt < 4; ++nt) {
            const int oo = nt * 16 + nbase;
            const size_t yi = (size_t)oo * VV + vgr;
            float y0v = bf2f(y0g[yi]);
            float y1v = bf2f(y1g[yi]);
            float y2v = bf2f(y2g[yi]);
            float val = acc[nt][r] + Ad * y0v + w1 * y1v + w2 * y2v;
            obt[(size_t)vgr * OO + oo] = fmaxf(val, 0.0f);
        }
    }
}

// =====================================================================
// Fallback (R4 path, verbatim): used only if ws_size < WS_NEED
// =====================================================================
__global__ __launch_bounds__(256, 4)
void y_kernel_fb(const float* __restrict__ x, const float* __restrict__ Theta,
                 unsigned short* __restrict__ yT)
{
    __shared__ __align__(16) unsigned char smem[32768];
    short* xT = (short*)(smem);
    const int tid = threadIdx.x, lane = tid & 63, q = tid >> 6;
    const int g = lane >> 4, nbase = lane & 15;
    const int bt = blockIdx.x >> 3;
    const int u0 = (blockIdx.x & 7) * 64;
    {
        const float* xp = x + ((size_t)(bt * VV + u0 + lane)) * FF + q * 16;
        float4 a0 = ((const float4*)xp)[0];
        float4 a1 = ((const float4*)xp)[1];
        float4 a2 = ((const float4*)xp)[2];
        float4 a3 = ((const float4*)xp)[3];
        float v[16] = {a0.x,a0.y,a0.z,a0.w, a1.x,a1.y,a1.z,a1.w,
                       a2.x,a2.y,a2.z,a2.w, a3.x,a3.y,a3.z,a3.w};
        s16x8 p0, p1;
        #pragma unroll
        for (int e = 0; e < 8; ++e) { p0[e] = f2bf(v[e]); p1[e] = f2bf(v[8 + e]); }
        const int fs = swz(lane);
        *(s16x8*)&xT[lane * 64 + (((q * 2)     ^ fs) * 8)] = p0;
        *(s16x8*)&xT[lane * 64 + (((q * 2 + 1) ^ fs) * 8)] = p1;
    }
    #pragma unroll
    for (int k = 0; k < 3; ++k) {
        short* tk = (short*)(smem + 8192 + k * 8192);
        s16x8 p0, p1;
        #pragma unroll
        for (int e = 0; e < 8; ++e) {
            p0[e] = f2bf(Theta[k * FF * OO + (q * 16 + e) * OO + lane]);
            p1[e] = f2bf(Theta[k * FF * OO + (q * 16 + 8 + e) * OO + lane]);
        }
        const int fs = swz(lane);
        *(s16x8*)&tk[lane * 64 + (((q * 2)     ^ fs) * 8)] = p0;
        *(s16x8*)&tk[lane * 64 + (((q * 2 + 1) ^ fs) * 8)] = p1;
    }
    __syncthreads();
    f32x4 zero = {0.f, 0.f, 0.f, 0.f};
    f32x4 acc[3][4];
    #pragma unroll
    for (int k = 0; k < 3; ++k)
        #pragma unroll
        for (int nt = 0; nt < 4; ++nt) acc[k][nt] = zero;
    const int mrow = q * 16 + nbase;
    const int moff = mrow * 64, ms = swz(mrow);
    #pragma unroll
    for (int kk = 0; kk < 2; ++kk) {
        const int slotA = kk * 4 + g;
        s16x8 a = *(const s16x8*)&xT[moff + ((slotA ^ ms) * 8)];
        #pragma unroll
        for (int nt = 0; nt < 4; ++nt) {
            const int nrow = nt * 16 + nbase;
            const int nad = nrow * 64 + ((slotA ^ swz(nrow)) * 8);
            #pragma unroll
            for (int k = 0; k < 3; ++k) {
                s16x8 bb = *(const s16x8*)&((short*)(smem + 8192 + k * 8192))[nad];
                acc[k][nt] = __builtin_amdgcn_mfma_f32_16x16x32_bf16(a, bb, acc[k][nt], 0, 0, 0);
            }
        }
    }
    #pragma unroll
    for (int k = 0; k < 3; ++k) {
        #pragma unroll
        for (int nt = 0; nt < 4; ++nt) {
            const int o = nt * 16 + nbase;
            const int u = u0 + q * 16 + g * 4;
            u16x4 pk;
            #pragma unroll
            for (int r = 0; r < 4; ++r) pk[r] = (unsigned short)f2bf(acc[k][nt][r]);
            *(u16x4*)&yT[(size_t)k * YELEMS + ((size_t)(bt * 64 + o)) * VV + u] = pk;
        }
    }
}

__global__ __launch_bounds__(256, 4)
void cheb_main_fb(const float* __restrict__ S, const float* __restrict__ Att,
                  const unsigned short* __restrict__ yT, float* __restrict__ out)
{
    const int tid = threadIdx.x, lane = tid & 63, q = tid >> 6;
    const int g = lane >> 4, nbase = lane & 15;
    const int wg = blockIdx.x;
    const int bt = (wg & 7) + ((wg >> 6) << 3);
    const int vt = (wg >> 3) & 7;
    const int v0 = vt * 64;
    const int b  = bt >> 4;
    const float* Sbt = S + (size_t)bt * VV * VV;
    const float* Abt = Att + (size_t)b * VV * VV;
    const unsigned short* y0g = yT + (size_t)bt * 64 * VV;
    const unsigned short* y1g = y0g + (size_t)YELEMS;
    const unsigned short* y2g = y0g + (size_t)2 * YELEMS;
    const int mrow = q * 16 + nbase;
    const int vg   = v0 + mrow;
    const float* Srow = Sbt + (size_t)vg * VV;
    const float* Scol = Sbt + vg;
    const float* Acol = Abt + vg;
    f32x4 zero = {0.f, 0.f, 0.f, 0.f};
    f32x4 acc[4];
    #pragma unroll
    for (int i = 0; i < 4; ++i) acc[i] = zero;
    float da0 = 0.f, da1 = 0.f, adg = 0.f, sdg = 0.f;
    #pragma unroll
    for (int ut = 0; ut < 8; ++ut) {
        const int u0t = ut * 64;
        #pragma unroll
        for (int kk = 0; kk < 2; ++kk) {
            const int ub = u0t + (kk * 4 + g) * 8;
            s16x8 b10 = *(const s16x8*)&y1g[(size_t)(0 * 16 + nbase) * VV + ub];
            s16x8 b11 = *(const s16x8*)&y1g[(size_t)(1 * 16 + nbase) * VV + ub];
            s16x8 b12 = *(const s16x8*)&y1g[(size_t)(2 * 16 + nbase) * VV + ub];
            s16x8 b13 = *(const s16x8*)&y1g[(size_t)(3 * 16 + nbase) * VV + ub];
            f32x4 r0 = *(const f32x4*)(Srow + ub);
            f32x4 r1 = *(const f32x4*)(Srow + ub + 4);
            s16x8 a1, a2;
            #pragma unroll
            for (int e = 0; e < 8; ++e) {
                float sc = Scol[(size_t)(ub + e) * VV];
                float av = Acol[(size_t)(ub + e) * VV];
                float rv = (e < 4) ? r0[e] : r1[e - 4];
                float sm = fminf(sc, rv);
                if (e & 1) da1 += sm; else da0 += sm;
                float c1 = -av * sm;
                float c2 = (av + av) * (sm * sm);
                if (ub + e == vg) { c1 = 0.f; c2 = 0.f; adg = av; sdg = sm; }
                a1[e] = f2bf(c1);
                a2[e] = f2bf(c2);
            }
            acc[0] = __builtin_amdgcn_mfma_f32_16x16x32_bf16(a1, b10, acc[0], 0, 0, 0);
            acc[1] = __builtin_amdgcn_mfma_f32_16x16x32_bf16(a1, b11, acc[1], 0, 0, 0);
            acc[2] = __builtin_amdgcn_mfma_f32_16x16x32_bf16(a1, b12, acc[2], 0, 0, 0);
            acc[3] = __builtin_amdgcn_mfma_f32_16x16x32_bf16(a1, b13, acc[3], 0, 0, 0);
            s16x8 b20 = *(const s16x8*)&y2g[(size_t)(0 * 16 + nbase) * VV + ub];
            s16x8 b21 = *(const s16x8*)&y2g[(size_t)(1 * 16 + nbase) * VV + ub];
            s16x8 b22 = *(const s16x8*)&y2g[(size_t)(2 * 16 + nbase) * VV + ub];
            s16x8 b23 = *(const s16x8*)&y2g[(size_t)(3 * 16 + nbase) * VV + ub];
            acc[0] = __builtin_amdgcn_mfma_f32_16x16x32_bf16(a2, b20, acc[0], 0, 0, 0);
            acc[1] = __builtin_amdgcn_mfma_f32_16x16x32_bf16(a2, b21, acc[1], 0, 0, 0);
            acc[2] = __builtin_amdgcn_mfma_f32_16x16x32_bf16(a2, b22, acc[2], 0, 0, 0);
            acc[3] = __builtin_amdgcn_mfma_f32_16x16x32_bf16(a2, b23, acc[3], 0, 0, 0);
        }
    }
    float da = da0 + da1;
    da  += __shfl_xor(da, 16);  da  += __shfl_xor(da, 32);
    adg += __shfl_xor(adg, 16); adg += __shfl_xor(adg, 32);
    sdg += __shfl_xor(sdg, 16); sdg += __shfl_xor(sdg, 32);
    float* obt = out + (size_t)bt * VV * OO;
    #pragma unroll
    for (int r = 0; r < 4; ++r) {
        const int vloc = q * 16 + g * 4 + r;
        const int src  = g * 4 + r;
        const float Ad = __shfl(adg, src);
        const float dv = __shfl(da,  src);
        const float Sd = __shfl(sdg, src);
        const float Ld = dv - Sd - 1.0f;
        const float w1 = Ad * Ld;
        const float w2 = Ad * (2.0f * Ld * Ld - 1.0f);
        const int vgr = v0 + vloc;
        #pragma unroll
        for (int nt = 0; nt < 4; ++nt) {
            const int oo = nt * 16 + nbase;
            const size_t yi = (size_t)oo * VV + vgr;
            float y0v = bf2f(y0g[yi]);
            float y1v = bf2f(y1g[yi]);
            float y2v = bf2f(y2g[yi]);
            float val = acc[nt][r] + Ad * y0v + w1 * y1v + w2 * y2v;
            obt[(size_t)vgr * OO + oo] = fmaxf(val, 0.0f);
        }
    }
}

extern "C" void kernel_launch(void* const* d_in, const int* in_sizes, int n_in,
                              void* d_out, int out_size, void* d_ws, size_t ws_size,
                              hipStream_t stream) {
    (void)in_sizes; (void)n_in; (void)out_size;
    const float* x   = (const float*)d_in[0];
    const float* Att = (const float*)d_in[1];
    const float* S   = (const float*)d_in[2];
    const float* Th  = (const float*)d_in[3];
    float* outp = (float*)d_out;
    if (ws_size >= (size_t)WS_NEED) {
        unsigned char* ws = (unsigned char*)d_ws;
        hipLaunchKernelGGL(coef_kernel, dim3(9216), dim3(256), 0, stream, S, Att, ws);
        hipLaunchKernelGGL(y_kernel2, dim3(2048), dim3(256), 0, stream, x, Th, ws);
        hipLaunchKernelGGL(cheb_b, dim3(2048), dim3(256), 0, stream, ws, outp);
    } else {
        unsigned short* yT = (unsigned short*)d_ws;
        hipLaunchKernelGGL(y_kernel_fb, dim3(2048), dim3(256), 0, stream, x, Th, yT);
        hipLaunchKernelGGL(cheb_main_fb, dim3(2048), dim3(256), 0, stream, S, Att, yT, outp);
    }
}

// Round 8
// 200.558 us; speedup vs baseline: 2.8578x; 1.5081x over previous
//
#include <hip/hip_runtime.h>

#define VV 512
#define FF 64
#define OO 64
#define YELEMS 8388608  // shorts per bf16 y tensor (256*64*512)

// ---- workspace layout (bytes) ----
#define C1_OFF    0u
#define C2_OFF    67108864u
#define Y1F8_OFF  134217728u
#define Y2F8_OFF  142606336u
#define YB_OFF    150994944u
#define DEGP_OFF  201326592u
#define SDG_OFF   205520896u
#define ADG_OFF   206045184u
#define WS_NEED   206569472u

using f32x4 = __attribute__((ext_vector_type(4))) float;
using s16x8 = __attribute__((ext_vector_type(8))) short;
using u16x4 = __attribute__((ext_vector_type(4))) unsigned short;

__device__ __forceinline__ short f2bf(float f) {
    union { float f; unsigned int u; } v; v.f = f;
    unsigned int u = v.u;
    u += 0x7fffu + ((u >> 16) & 1u);
    return (short)(u >> 16);
}
__device__ __forceinline__ float bf2f(unsigned short u) {
    union { unsigned int u; float f; } v; v.u = ((unsigned int)u) << 16; return v.f;
}
__device__ __forceinline__ int swz(int row) { return (row >> 1) & 7; }

__device__ __forceinline__ void gload16(const void* g, void* l) {
    __builtin_amdgcn_global_load_lds(
        (const __attribute__((address_space(1))) unsigned int*)g,
        (__attribute__((address_space(3))) unsigned int*)l, 16, 0, 0);
}

// =====================================================================
// Kernel A: coefficient tiles -> fp8, transposed [bt][v][u]; deg partials
// =====================================================================
__device__ __forceinline__ void coef_pass(
    const float (*Tuv)[65], const float (*Tvu)[65], const float (*Auv)[65],
    float (*degred)[64], unsigned char* c1out, unsigned char* c2out,
    int tid, bool isdiag, float* SdgW, float* AdgW)
{
    const int uq = (tid & 15) * 4;
    const int vrow = tid >> 4;
    float dd0 = 0.f, dd1 = 0.f, dd2 = 0.f, dd3 = 0.f;
    #pragma unroll
    for (int it = 0; it < 4; ++it) {
        const int v = vrow + it * 16;
        float c1v[4], c2v[4];
        #pragma unroll
        for (int e = 0; e < 4; ++e) {
            float sm = fminf(Tuv[uq + e][v], Tvu[v][uq + e]);
            float a  = Auv[uq + e][v];
            if (e == 0) dd0 += sm; else if (e == 1) dd1 += sm;
            else if (e == 2) dd2 += sm; else dd3 += sm;
            float c1 = -a * sm;
            float c2 = (a + a) * (sm * sm);
            if (isdiag && (uq + e == v)) {
                c1 = 0.f; c2 = 0.f;
                SdgW[v] = sm; AdgW[v] = a;
            }
            c1v[e] = c1; c2v[e] = c2;
        }
        int w1 = __builtin_amdgcn_cvt_pk_fp8_f32(c1v[0], c1v[1], 0, false);
        w1     = __builtin_amdgcn_cvt_pk_fp8_f32(c1v[2], c1v[3], w1, true);
        int w2 = __builtin_amdgcn_cvt_pk_fp8_f32(c2v[0], c2v[1], 0, false);
        w2     = __builtin_amdgcn_cvt_pk_fp8_f32(c2v[2], c2v[3], w2, true);
        *(int*)(c1out + (size_t)v * VV + uq) = w1;
        *(int*)(c2out + (size_t)v * VV + uq) = w2;
    }
    degred[vrow][uq + 0] = dd0;
    degred[vrow][uq + 1] = dd1;
    degred[vrow][uq + 2] = dd2;
    degred[vrow][uq + 3] = dd3;
}

__global__ __launch_bounds__(256, 2)
void coef_kernel(const float* __restrict__ S, const float* __restrict__ Att,
                 unsigned char* __restrict__ ws)
{
    __shared__ float Tij[64][65];
    __shared__ float Tji[64][65];
    __shared__ float Aij[64][65];
    __shared__ float Aji[64][65];
    __shared__ float degA[16][64];
    __shared__ float degB[16][64];

    const int tid = threadIdx.x;
    const int bt = blockIdx.x / 36;
    int p = blockIdx.x - bt * 36;
    int i = 0;
    while (p >= 8 - i) { p -= 8 - i; ++i; }
    const int j = i + p;
    const int b = bt >> 4;
    const int u0i = i * 64, u0j = j * 64;

    const float* Sbt = S + (size_t)bt * VV * VV;
    const float* Abt = Att + (size_t)b * VV * VV;

    {
        const int r = tid >> 2, c4 = (tid & 3) * 16;
        const float* gij = Sbt + (size_t)(u0i + r) * VV + u0j + c4;
        const float* gji = Sbt + (size_t)(u0j + r) * VV + u0i + c4;
        const float* aij = Abt + (size_t)(u0i + r) * VV + u0j + c4;
        const float* aji = Abt + (size_t)(u0j + r) * VV + u0i + c4;
        #pragma unroll
        for (int w = 0; w < 4; ++w) {
            float4 t = ((const float4*)gij)[w];
            Tij[r][c4 + w * 4 + 0] = t.x; Tij[r][c4 + w * 4 + 1] = t.y;
            Tij[r][c4 + w * 4 + 2] = t.z; Tij[r][c4 + w * 4 + 3] = t.w;
        }
        #pragma unroll
        for (int w = 0; w < 4; ++w) {
            float4 t = ((const float4*)gji)[w];
            Tji[r][c4 + w * 4 + 0] = t.x; Tji[r][c4 + w * 4 + 1] = t.y;
            Tji[r][c4 + w * 4 + 2] = t.z; Tji[r][c4 + w * 4 + 3] = t.w;
        }
        #pragma unroll
        for (int w = 0; w < 4; ++w) {
            float4 t = ((const float4*)aij)[w];
            Aij[r][c4 + w * 4 + 0] = t.x; Aij[r][c4 + w * 4 + 1] = t.y;
            Aij[r][c4 + w * 4 + 2] = t.z; Aij[r][c4 + w * 4 + 3] = t.w;
        }
        #pragma unroll
        for (int w = 0; w < 4; ++w) {
            float4 t = ((const float4*)aji)[w];
            Aji[r][c4 + w * 4 + 0] = t.x; Aji[r][c4 + w * 4 + 1] = t.y;
            Aji[r][c4 + w * 4 + 2] = t.z; Aji[r][c4 + w * 4 + 3] = t.w;
        }
    }
    __syncthreads();

    unsigned char* c1w = ws + C1_OFF + (size_t)bt * (VV * VV);
    unsigned char* c2w = ws + C2_OFF + (size_t)bt * (VV * VV);
    float* SdgW = (float*)(ws + SDG_OFF) + (size_t)bt * VV;
    float* AdgW = (float*)(ws + ADG_OFF) + (size_t)bt * VV;
    float* degpW = (float*)(ws + DEGP_OFF) + (size_t)bt * 8 * VV;

    coef_pass(Tij, Tji, Aij, degA,
              c1w + (size_t)u0j * VV + u0i, c2w + (size_t)u0j * VV + u0i,
              tid, (i == j), SdgW + u0j, AdgW + u0j);
    if (i < j) {
        coef_pass(Tji, Tij, Aji, degB,
                  c1w + (size_t)u0i * VV + u0j, c2w + (size_t)u0i * VV + u0j,
                  tid, false, SdgW, AdgW);
    }
    __syncthreads();

    if (tid < 64) {
        float s = 0.f;
        #pragma unroll
        for (int k = 0; k < 16; ++k) s += degA[k][tid];
        degpW[(size_t)j * VV + u0i + tid] = s;
    } else if (tid < 128 && i < j) {
        float s = 0.f;
        #pragma unroll
        for (int k = 0; k < 16; ++k) s += degB[k][tid - 64];
        degpW[(size_t)i * VV + u0j + (tid - 64)] = s;
    }
}

// =====================================================================
// Kernel A': y_k = x @ Theta_k ; bf16 [k][bt][o][u] + swizzled fp8 images
// fp8 image addr: o*512 + ((s & ~7) | ((s&7) ^ (o&7)))*8 + (u&7),  s = u>>3
// =====================================================================
__global__ __launch_bounds__(256, 4)
void y_kernel2(const float* __restrict__ x, const float* __restrict__ Theta,
               unsigned char* __restrict__ ws)
{
    __shared__ __align__(16) unsigned char smem[32768];
    short* xT = (short*)(smem);

    const int tid = threadIdx.x, lane = tid & 63, q = tid >> 6;
    const int g = lane >> 4, nbase = lane & 15;
    const int bt = blockIdx.x >> 3;
    const int u0 = (blockIdx.x & 7) * 64;

    {
        const float* xp = x + ((size_t)(bt * VV + u0 + lane)) * FF + q * 16;
        float4 a0 = ((const float4*)xp)[0];
        float4 a1 = ((const float4*)xp)[1];
        float4 a2 = ((const float4*)xp)[2];
        float4 a3 = ((const float4*)xp)[3];
        float v[16] = {a0.x,a0.y,a0.z,a0.w, a1.x,a1.y,a1.z,a1.w,
                       a2.x,a2.y,a2.z,a2.w, a3.x,a3.y,a3.z,a3.w};
        s16x8 p0, p1;
        #pragma unroll
        for (int e = 0; e < 8; ++e) { p0[e] = f2bf(v[e]); p1[e] = f2bf(v[8 + e]); }
        const int fs = swz(lane);
        *(s16x8*)&xT[lane * 64 + (((q * 2)     ^ fs) * 8)] = p0;
        *(s16x8*)&xT[lane * 64 + (((q * 2 + 1) ^ fs) * 8)] = p1;
    }
    #pragma unroll
    for (int k = 0; k < 3; ++k) {
        short* tk = (short*)(smem + 8192 + k * 8192);
        s16x8 p0, p1;
        #pragma unroll
        for (int e = 0; e < 8; ++e) {
            p0[e] = f2bf(Theta[k * FF * OO + (q * 16 + e) * OO + lane]);
            p1[e] = f2bf(Theta[k * FF * OO + (q * 16 + 8 + e) * OO + lane]);
        }
        const int fs = swz(lane);
        *(s16x8*)&tk[lane * 64 + (((q * 2)     ^ fs) * 8)] = p0;
        *(s16x8*)&tk[lane * 64 + (((q * 2 + 1) ^ fs) * 8)] = p1;
    }
    __syncthreads();

    f32x4 zero = {0.f, 0.f, 0.f, 0.f};
    f32x4 acc[3][4];
    #pragma unroll
    for (int k = 0; k < 3; ++k)
        #pragma unroll
        for (int nt = 0; nt < 4; ++nt) acc[k][nt] = zero;

    const int mrow = q * 16 + nbase;
    const int moff = mrow * 64, ms = swz(mrow);
    #pragma unroll
    for (int kk = 0; kk < 2; ++kk) {
        const int slotA = kk * 4 + g;
        s16x8 a = *(const s16x8*)&xT[moff + ((slotA ^ ms) * 8)];
        #pragma unroll
        for (int nt = 0; nt < 4; ++nt) {
            const int nrow = nt * 16 + nbase;
            const int nad = nrow * 64 + ((slotA ^ swz(nrow)) * 8);
            #pragma unroll
            for (int k = 0; k < 3; ++k) {
                s16x8 bb = *(const s16x8*)&((short*)(smem + 8192 + k * 8192))[nad];
                acc[k][nt] = __builtin_amdgcn_mfma_f32_16x16x32_bf16(a, bb, acc[k][nt], 0, 0, 0);
            }
        }
    }
    unsigned short* yb = (unsigned short*)(ws + YB_OFF);
    unsigned char* y1f8 = ws + Y1F8_OFF + (size_t)bt * 32768;
    unsigned char* y2f8 = ws + Y2F8_OFF + (size_t)bt * 32768;
    #pragma unroll
    for (int k = 0; k < 3; ++k) {
        #pragma unroll
        for (int nt = 0; nt < 4; ++nt) {
            const int o = nt * 16 + nbase;
            const int u = u0 + q * 16 + g * 4;
            u16x4 pk;
            #pragma unroll
            for (int r = 0; r < 4; ++r) pk[r] = (unsigned short)f2bf(acc[k][nt][r]);
            *(u16x4*)&yb[(size_t)k * YELEMS + ((size_t)(bt * 64 + o)) * VV + u] = pk;
            if (k >= 1) {
                const int s = u >> 3;
                const int sw = (s & ~7) | ((s & 7) ^ (o & 7));
                const int ad = o * 512 + sw * 8 + (u & 4);
                int w = __builtin_amdgcn_cvt_pk_fp8_f32(acc[k][nt][0], acc[k][nt][1], 0, false);
                w     = __builtin_amdgcn_cvt_pk_fp8_f32(acc[k][nt][2], acc[k][nt][3], w, true);
                if (k == 1) *(int*)(y1f8 + ad) = w;
                else        *(int*)(y2f8 + ad) = w;
            }
        }
    }
}

// =====================================================================
// Kernel B: fp8 GEMM. y tiles staged once via global_load_lds; all
// A-fragments preloaded to registers; K-loop = ds_read + MFMA only.
// =====================================================================
__global__ __launch_bounds__(256, 2)
void cheb_b(const unsigned char* __restrict__ ws, float* __restrict__ out)
{
    __shared__ __align__(16) unsigned char yLds[65536];  // y1 image | y2 image

    const int tid = threadIdx.x, lane = tid & 63, q = tid >> 6;
    const int g = lane >> 4, nbase = lane & 15;

    const int wg = blockIdx.x;
    const int bt = (wg & 7) + ((wg >> 6) << 3);
    const int vt = (wg >> 3) & 7;
    const int v0 = vt * 64;

    const int mrow = q * 16 + nbase;
    const int vg   = v0 + mrow;

    // stage y1+y2 fp8 images (64 KB) -> LDS, linear dest (images pre-swizzled)
    {
        const unsigned char* y1img = ws + Y1F8_OFF + (size_t)bt * 32768;
        const unsigned char* y2img = ws + Y2F8_OFF + (size_t)bt * 32768;
        const int wo = q * 1024 + lane * 16;
        #pragma unroll
        for (int i = 0; i < 8; ++i) {
            gload16(y1img + i * 4096 + wo, (char*)yLds + i * 4096 + q * 1024);
            gload16(y2img + i * 4096 + wo, (char*)yLds + 32768 + i * 4096 + q * 1024);
        }
    }

    // preload ALL A-fragments (c1,c2): 32 independent 8B loads -> 64 VGPR
    const unsigned char* c1r = ws + C1_OFF + (size_t)bt * (VV * VV) + (size_t)vg * VV + g * 8;
    const unsigned char* c2r = ws + C2_OFF + (size_t)bt * (VV * VV) + (size_t)vg * VV + g * 8;
    long c1f[16], c2f[16];
    #pragma unroll
    for (int it = 0; it < 16; ++it) {
        c1f[it] = *(const long*)(c1r + it * 32);   // col = ut*64 + kk*32 + g*8
        c2f[it] = *(const long*)(c2r + it * 32);
    }

    __syncthreads();   // drains vmcnt(0): LDS staged, c-frags resident

    f32x4 zero = {0.f, 0.f, 0.f, 0.f};
    f32x4 acc[4];
    #pragma unroll
    for (int i = 0; i < 4; ++i) acc[i] = zero;

    #pragma unroll
    for (int ut = 0; ut < 8; ++ut) {
        #pragma unroll
        for (int kk = 0; kk < 2; ++kk) {
            const int it = ut * 2 + kk;
            const long a1 = c1f[it];
            const long a2 = c2f[it];
            #pragma unroll
            for (int nt = 0; nt < 4; ++nt) {
                const int o = nt * 16 + nbase;
                const int ad = o * 512 + (ut * 8 + ((kk * 4 + g) ^ (o & 7))) * 8;
                long b1 = *(const long*)&yLds[ad];
                long b2 = *(const long*)&yLds[32768 + ad];
                acc[nt] = __builtin_amdgcn_mfma_f32_16x16x32_fp8_fp8(a1, b1, acc[nt], 0, 0, 0);
                acc[nt] = __builtin_amdgcn_mfma_f32_16x16x32_fp8_fp8(a2, b2, acc[nt], 0, 0, 0);
            }
        }
    }

    // epilogue: exact diagonal path + combine
    const unsigned short* y0g = (const unsigned short*)(ws + YB_OFF) + (size_t)bt * 64 * VV;
    const unsigned short* y1g = y0g + (size_t)YELEMS;
    const unsigned short* y2g = y0g + (size_t)2 * YELEMS;
    const float* degp = (const float*)(ws + DEGP_OFF) + (size_t)bt * 8 * VV;
    const float* SdgW = (const float*)(ws + SDG_OFF) + (size_t)bt * VV;
    const float* AdgW = (const float*)(ws + ADG_OFF) + (size_t)bt * VV;

    float* obt = out + (size_t)bt * VV * OO;
    #pragma unroll
    for (int r = 0; r < 4; ++r) {
        const int vloc = q * 16 + g * 4 + r;
        const int vgr = v0 + vloc;
        float dv = 0.f;
        #pragma unroll
        for (int s = 0; s < 8; ++s) dv += degp[(size_t)s * VV + vgr];
        const float Ad = AdgW[vgr];
        const float Sd = SdgW[vgr];
        const float Ld = dv - Sd - 1.0f;
        const float w1 = Ad * Ld;
        const float w2 = Ad * (2.0f * Ld * Ld - 1.0f);
        #pragma unroll
        for (int nt = 0; nt < 4; ++nt) {
            const int oo = nt * 16 + nbase;
            const size_t yi = (size_t)oo * VV + vgr;
            float y0v = bf2f(y0g[yi]);
            float y1v = bf2f(y1g[yi]);
            float y2v = bf2f(y2g[yi]);
            float val = acc[nt][r] + Ad * y0v + w1 * y1v + w2 * y2v;
            obt[(size_t)vgr * OO + oo] = fmaxf(val, 0.0f);
        }
    }
}

// =====================================================================
// Fallback (R4 path, verbatim): used only if ws_size < WS_NEED
// =====================================================================
__global__ __launch_bounds__(256, 4)
void y_kernel_fb(const float* __restrict__ x, const float* __restrict__ Theta,
                 unsigned short* __restrict__ yT)
{
    __shared__ __align__(16) unsigned char smem[32768];
    short* xT = (short*)(smem);
    const int tid = threadIdx.x, lane = tid & 63, q = tid >> 6;
    const int g = lane >> 4, nbase = lane & 15;
    const int bt = blockIdx.x >> 3;
    const int u0 = (blockIdx.x & 7) * 64;
    {
        const float* xp = x + ((size_t)(bt * VV + u0 + lane)) * FF + q * 16;
        float4 a0 = ((const float4*)xp)[0];
        float4 a1 = ((const float4*)xp)[1];
        float4 a2 = ((const float4*)xp)[2];
        float4 a3 = ((const float4*)xp)[3];
        float v[16] = {a0.x,a0.y,a0.z,a0.w, a1.x,a1.y,a1.z,a1.w,
                       a2.x,a2.y,a2.z,a2.w, a3.x,a3.y,a3.z,a3.w};
        s16x8 p0, p1;
        #pragma unroll
        for (int e = 0; e < 8; ++e) { p0[e] = f2bf(v[e]); p1[e] = f2bf(v[8 + e]); }
        const int fs = swz(lane);
        *(s16x8*)&xT[lane * 64 + (((q * 2)     ^ fs) * 8)] = p0;
        *(s16x8*)&xT[lane * 64 + (((q * 2 + 1) ^ fs) * 8)] = p1;
    }
    #pragma unroll
    for (int k = 0; k < 3; ++k) {
        short* tk = (short*)(smem + 8192 + k * 8192);
        s16x8 p0, p1;
        #pragma unroll
        for (int e = 0; e < 8; ++e) {
            p0[e] = f2bf(Theta[k * FF * OO + (q * 16 + e) * OO + lane]);
            p1[e] = f2bf(Theta[k * FF * OO + (q * 16 + 8 + e) * OO + lane]);
        }
        const int fs = swz(lane);
        *(s16x8*)&tk[lane * 64 + (((q * 2)     ^ fs) * 8)] = p0;
        *(s16x8*)&tk[lane * 64 + (((q * 2 + 1) ^ fs) * 8)] = p1;
    }
    __syncthreads();
    f32x4 zero = {0.f, 0.f, 0.f, 0.f};
    f32x4 acc[3][4];
    #pragma unroll
    for (int k = 0; k < 3; ++k)
        #pragma unroll
        for (int nt = 0; nt < 4; ++nt) acc[k][nt] = zero;
    const int mrow = q * 16 + nbase;
    const int moff = mrow * 64, ms = swz(mrow);
    #pragma unroll
    for (int kk = 0; kk < 2; ++kk) {
        const int slotA = kk * 4 + g;
        s16x8 a = *(const s16x8*)&xT[moff + ((slotA ^ ms) * 8)];
        #pragma unroll
        for (int nt = 0; nt < 4; ++nt) {
            const int nrow = nt * 16 + nbase;
            const int nad = nrow * 64 + ((slotA ^ swz(nrow)) * 8);
            #pragma unroll
            for (int k = 0; k < 3; ++k) {
                s16x8 bb = *(const s16x8*)&((short*)(smem + 8192 + k * 8192))[nad];
                acc[k][nt] = __builtin_amdgcn_mfma_f32_16x16x32_bf16(a, bb, acc[k][nt], 0, 0, 0);
            }
        }
    }
    #pragma unroll
    for (int k = 0; k < 3; ++k) {
        #pragma unroll
        for (int nt = 0; nt < 4; ++nt) {
            const int o = nt * 16 + nbase;
            const int u = u0 + q * 16 + g * 4;
            u16x4 pk;
            #pragma unroll
            for (int r = 0; r < 4; ++r) pk[r] = (unsigned short)f2bf(acc[k][nt][r]);
            *(u16x4*)&yT[(size_t)k * YELEMS + ((size_t)(bt * 64 + o)) * VV + u] = pk;
        }
    }
}

__global__ __launch_bounds__(256, 4)
void cheb_main_fb(const float* __restrict__ S, const float* __restrict__ Att,
                  const unsigned short* __restrict__ yT, float* __restrict__ out)
{
    const int tid = threadIdx.x, lane = tid & 63, q = tid >> 6;
    const int g = lane >> 4, nbase = lane & 15;
    const int wg = blockIdx.x;
    const int bt = (wg & 7) + ((wg >> 6) << 3);
    const int vt = (wg >> 3) & 7;
    const int v0 = vt * 64;
    const int b  = bt >> 4;
    const float* Sbt = S + (size_t)bt * VV * VV;
    const float* Abt = Att + (size_t)b * VV * VV;
    const unsigned short* y0g = yT + (size_t)bt * 64 * VV;
    const unsigned short* y1g = y0g + (size_t)YELEMS;
    const unsigned short* y2g = y0g + (size_t)2 * YELEMS;
    const int mrow = q * 16 + nbase;
    const int vg   = v0 + mrow;
    const float* Srow = Sbt + (size_t)vg * VV;
    const float* Scol = Sbt + vg;
    const float* Acol = Abt + vg;
    f32x4 zero = {0.f, 0.f, 0.f, 0.f};
    f32x4 acc[4];
    #pragma unroll
    for (int i = 0; i < 4; ++i) acc[i] = zero;
    float da0 = 0.f, da1 = 0.f, adg = 0.f, sdg = 0.f;
    #pragma unroll
    for (int ut = 0; ut < 8; ++ut) {
        const int u0t = ut * 64;
        #pragma unroll
        for (int kk = 0; kk < 2; ++kk) {
            const int ub = u0t + (kk * 4 + g) * 8;
            s16x8 b10 = *(const s16x8*)&y1g[(size_t)(0 * 16 + nbase) * VV + ub];
            s16x8 b11 = *(const s16x8*)&y1g[(size_t)(1 * 16 + nbase) * VV + ub];
            s16x8 b12 = *(const s16x8*)&y1g[(size_t)(2 * 16 + nbase) * VV + ub];
            s16x8 b13 = *(const s16x8*)&y1g[(size_t)(3 * 16 + nbase) * VV + ub];
            f32x4 r0 = *(const f32x4*)(Srow + ub);
            f32x4 r1 = *(const f32x4*)(Srow + ub + 4);
            s16x8 a1, a2;
            #pragma unroll
            for (int e = 0; e < 8; ++e) {
                float sc = Scol[(size_t)(ub + e) * VV];
                float av = Acol[(size_t)(ub + e) * VV];
                float rv = (e < 4) ? r0[e] : r1[e - 4];
                float sm = fminf(sc, rv);
                if (e & 1) da1 += sm; else da0 += sm;
                float c1 = -av * sm;
                float c2 = (av + av) * (sm * sm);
                if (ub + e == vg) { c1 = 0.f; c2 = 0.f; adg = av; sdg = sm; }
                a1[e] = f2bf(c1);
                a2[e] = f2bf(c2);
            }
            acc[0] = __builtin_amdgcn_mfma_f32_16x16x32_bf16(a1, b10, acc[0], 0, 0, 0);
            acc[1] = __builtin_amdgcn_mfma_f32_16x16x32_bf16(a1, b11, acc[1], 0, 0, 0);
            acc[2] = __builtin_amdgcn_mfma_f32_16x16x32_bf16(a1, b12, acc[2], 0, 0, 0);
            acc[3] = __builtin_amdgcn_mfma_f32_16x16x32_bf16(a1, b13, acc[3], 0, 0, 0);
            s16x8 b20 = *(const s16x8*)&y2g[(size_t)(0 * 16 + nbase) * VV + ub];
            s16x8 b21 = *(const s16x8*)&y2g[(size_t)(1 * 16 + nbase) * VV + ub];
            s16x8 b22 = *(const s16x8*)&y2g[(size_t)(2 * 16 + nbase) * VV + ub];
            s16x8 b23 = *(const s16x8*)&y2g[(size_t)(3 * 16 + nbase) * VV + ub];
            acc[0] = __builtin_amdgcn_mfma_f32_16x16x32_bf16(a2, b20, acc[0], 0, 0, 0);
            acc[1] = __builtin_amdgcn_mfma_f32_16x16x32_bf16(a2, b21, acc[1], 0, 0, 0);
            acc[2] = __builtin_amdgcn_mfma_f32_16x16x32_bf16(a2, b22, acc[2], 0, 0, 0);
            acc[3] = __builtin_amdgcn_mfma_f32_16x16x32_bf16(a2, b23, acc[3], 0, 0, 0);
        }
    }
    float da = da0 + da1;
    da  += __shfl_xor(da, 16);  da  += __shfl_xor(da, 32);
    adg += __shfl_xor(adg, 16); adg += __shfl_xor(adg, 32);
    sdg += __shfl_xor(sdg, 16); sdg += __shfl_xor(sdg, 32);
    float* obt = out + (size_t)bt * VV * OO;
    #pragma unroll
    for (int r = 0; r < 4; ++r) {
        const int vloc = q * 16 + g * 4 + r;
        const int src  = g * 4 + r;
        const float Ad = __shfl(adg, src);
        const float dv = __shfl(da,  src);
        const float Sd = __shfl(sdg, src);
        const float Ld = dv - Sd - 1.0f;
        const float w1 = Ad * Ld;
        const float w2 = Ad * (2.0f * Ld * Ld - 1.0f);
        const int vgr = v0 + vloc;
        #pragma unroll
        for (int nt = 0; nt < 4; ++nt) {
            const int oo = nt * 16 + nbase;
            const size_t yi = (size_t)oo * VV + vgr;
            float y0v = bf2f(y0g[yi]);
            float y1v = bf2f(y1g[yi]);
            float y2v = bf2f(y2g[yi]);
            float val = acc[nt][r] + Ad * y0v + w1 * y1v + w2 * y2v;
            obt[(size_t)vgr * OO + oo] = fmaxf(val, 0.0f);
        }
    }
}

extern "C" void kernel_launch(void* const* d_in, const int* in_sizes, int n_in,
                              void* d_out, int out_size, void* d_ws, size_t ws_size,
                              hipStream_t stream) {
    (void)in_sizes; (void)n_in; (void)out_size;
    const float* x   = (const float*)d_in[0];
    const float* Att = (const float*)d_in[1];
    const float* S   = (const float*)d_in[2];
    const float* Th  = (const float*)d_in[3];
    float* outp = (float*)d_out;
    if (ws_size >= (size_t)WS_NEED) {
        unsigned char* ws = (unsigned char*)d_ws;
        hipLaunchKernelGGL(coef_kernel, dim3(9216), dim3(256), 0, stream, S, Att, ws);
        hipLaunchKernelGGL(y_kernel2, dim3(2048), dim3(256), 0, stream, x, Th, ws);
        hipLaunchKernelGGL(cheb_b, dim3(2048), dim3(256), 0, stream, ws, outp);
    } else {
        unsigned short* yT = (unsigned short*)d_ws;
        hipLaunchKernelGGL(y_kernel_fb, dim3(2048), dim3(256), 0, stream, x, Th, yT);
        hipLaunchKernelGGL(cheb_main_fb, dim3(2048), dim3(256), 0, stream, S, Att, yT, outp);
    }
}